// Round 2
// baseline (980.370 us; speedup 1.0000x reference)
//
#include <hip/hip_runtime.h>
#include <math.h>

// Problem constants
#define N_TOKENS  16384
#define D_MODEL   4096
#define N_EXPERTS 64
#define CAPACITY  308          // ceil(1.2 * 16384 / 64)
#define BUCKET_CAP 1024

// GEMM tiling: lane = token, wave = 16 experts, block = 64 tokens x 64 experts.
// K split NK ways across blocks -> deterministic partial buffers in ws.
#define KTILE 64               // k per LDS staging chunk
#define XROW  68               // LDS row stride (floats); 68*4B, 16B aligned, 17%8==1 -> even b128 groups

// Output layout (float32 flat):
//   [0,32768) ids | [32768,65536) gates | [65536] aux | [65537,98305) mask

__global__ __launch_bounds__(256) void gemm_kernel(
    const float* __restrict__ x, const float* __restrict__ W,
    float* __restrict__ part,   // [NK][N_TOKENS][N_EXPERTS]
    int ksplit)
{
    __shared__ float xs[64 * XROW];   // 17408 B

    const int tid   = threadIdx.x;
    const int tg    = blockIdx.x & 255;     // token group (256 groups)
    const int nk    = blockIdx.x >> 8;      // k-split index
    const int tbase = tg * 64;
    const int kbase = nk * ksplit;
    const int lane  = tid & 63;
    const int wv    = __builtin_amdgcn_readfirstlane(tid >> 6);  // uniform wave id -> scalar W loads
    const int e0    = wv * 16;

    float acc[16];
    #pragma unroll
    for (int i = 0; i < 16; i++) acc[i] = 0.f;

    for (int kc = 0; kc < ksplit; kc += KTILE) {
        // ---- stage x tile: 64 tokens x 64 k, coalesced float4 ----
        #pragma unroll
        for (int r = 0; r < 4; r++) {
            int idx = tid + r * 256;
            int t   = idx >> 4;             // 0..63
            int k4  = (idx & 15) << 2;      // 0..60
            float4 v = *(const float4*)&x[(size_t)(tbase + t) * D_MODEL + kbase + kc + k4];
            *(float4*)&xs[t * XROW + k4] = v;
        }
        __syncthreads();

        // ---- compute: x frag from LDS (reused x16 experts), W via scalar loads ----
        #pragma unroll
        for (int kk = 0; kk < KTILE; kk += 16) {
            float4 xv0 = *(const float4*)&xs[lane * XROW + kk];
            float4 xv1 = *(const float4*)&xs[lane * XROW + kk + 4];
            float4 xv2 = *(const float4*)&xs[lane * XROW + kk + 8];
            float4 xv3 = *(const float4*)&xs[lane * XROW + kk + 12];
            const float* Wk = W + kbase + kc + kk;
            #pragma unroll
            for (int e = 0; e < 16; e++) {
                const float* wp = Wk + (size_t)(e0 + e) * D_MODEL;  // wave-uniform address
                float4 w0 = *(const float4*)(wp);
                float4 w1 = *(const float4*)(wp + 4);
                float4 w2 = *(const float4*)(wp + 8);
                float4 w3 = *(const float4*)(wp + 12);
                float s = acc[e];
                s = fmaf(xv0.x, w0.x, s); s = fmaf(xv0.y, w0.y, s);
                s = fmaf(xv0.z, w0.z, s); s = fmaf(xv0.w, w0.w, s);
                s = fmaf(xv1.x, w1.x, s); s = fmaf(xv1.y, w1.y, s);
                s = fmaf(xv1.z, w1.z, s); s = fmaf(xv1.w, w1.w, s);
                s = fmaf(xv2.x, w2.x, s); s = fmaf(xv2.y, w2.y, s);
                s = fmaf(xv2.z, w2.z, s); s = fmaf(xv2.w, w2.w, s);
                s = fmaf(xv3.x, w3.x, s); s = fmaf(xv3.y, w3.y, s);
                s = fmaf(xv3.z, w3.z, s); s = fmaf(xv3.w, w3.w, s);
                acc[e] = s;
            }
        }
        __syncthreads();
    }

    // ---- write partials: part[nk][tbase+lane][e0..e0+16) ----
    float4* dst = (float4*)&part[((size_t)nk * N_TOKENS + tbase + lane) * N_EXPERTS + e0];
    dst[0] = make_float4(acc[0],  acc[1],  acc[2],  acc[3]);
    dst[1] = make_float4(acc[4],  acc[5],  acc[6],  acc[7]);
    dst[2] = make_float4(acc[8],  acc[9],  acc[10], acc[11]);
    dst[3] = make_float4(acc[12], acc[13], acc[14], acc[15]);
}

// Combine partials + bias, softmax, top-2, bucket scatter, importance.
// 512 blocks x 256 threads; each wave handles 8 tokens, lane = expert.
__global__ __launch_bounds__(256) void topk_kernel(
    const float* __restrict__ part, const float* __restrict__ b, int NK,
    float* __restrict__ out_ids, float* __restrict__ out_gates,
    int* __restrict__ cnt, float* __restrict__ imp,
    float2* __restrict__ bucket, int bucket_cap)
{
    __shared__ float imp_s[4][N_EXPERTS];
    const int tid  = threadIdx.x;
    const int wave = tid >> 6;
    const int lane = tid & 63;
    float impacc = 0.f;

    for (int j = 0; j < 8; j++) {
        int tok = blockIdx.x * 32 + wave * 8 + j;

        float v = b[lane];
        for (int k = 0; k < NK; k++)   // fixed order -> deterministic
            v += part[((size_t)k * N_TOKENS + tok) * N_EXPERTS + lane];

        float m = v;
        #pragma unroll
        for (int s = 32; s > 0; s >>= 1) m = fmaxf(m, __shfl_xor(m, s));
        float p = expf(v - m);
        float sum = p;
        #pragma unroll
        for (int s = 32; s > 0; s >>= 1) sum += __shfl_xor(sum, s);
        float prob = p / sum;
        impacc += prob;

        // argmax #1 (lowest index wins ties, matching jax.lax.top_k)
        float bp = prob; int bi = lane;
        #pragma unroll
        for (int s = 32; s > 0; s >>= 1) {
            float op = __shfl_xor(bp, s); int oi = __shfl_xor(bi, s);
            if (op > bp || (op == bp && oi < bi)) { bp = op; bi = oi; }
        }
        // argmax #2 (exclude winner; probs >= 0 so -1 is -inf)
        float p2 = (lane == bi) ? -1.f : prob;
        float bp2 = p2; int bi2 = lane;
        #pragma unroll
        for (int s = 32; s > 0; s >>= 1) {
            float op = __shfl_xor(bp2, s); int oi = __shfl_xor(bi2, s);
            if (op > bp2 || (op == bp2 && oi < bi2)) { bp2 = op; bi2 = oi; }
        }

        if (lane == 0) {
            out_ids[tok * 2]       = (float)bi;
            out_ids[tok * 2 + 1]   = (float)bi2;
            out_gates[tok * 2]     = bp;
            out_gates[tok * 2 + 1] = bp2;
            int pos0 = atomicAdd(&cnt[bi], 1);
            if (pos0 < bucket_cap)
                bucket[bi * bucket_cap + pos0] = make_float2(bp, __int_as_float(tok * 2));
            int pos1 = atomicAdd(&cnt[bi2], 1);
            if (pos1 < bucket_cap)
                bucket[bi2 * bucket_cap + pos1] = make_float2(bp2, __int_as_float(tok * 2 + 1));
        }
    }

    imp_s[wave][lane] = impacc;
    __syncthreads();
    if (wave == 0) {
        float s = imp_s[0][lane] + imp_s[1][lane] + imp_s[2][lane] + imp_s[3][lane];
        atomicAdd(&imp[lane], s);
    }
}

// One block per expert: exact lexsort rank via O(n^2) comparison in LDS.
__global__ __launch_bounds__(256) void capacity_kernel(
    const int* __restrict__ cnt, const float2* __restrict__ bucket,
    float* __restrict__ out_mask, int bucket_cap)
{
    __shared__ float g_s[BUCKET_CAP];
    __shared__ int   i_s[BUCKET_CAP];
    const int e = blockIdx.x;
    int n = cnt[e];
    if (n > bucket_cap) n = bucket_cap;

    for (int i = threadIdx.x; i < n; i += 256) {
        float2 r = bucket[e * bucket_cap + i];
        g_s[i] = r.x;
        i_s[i] = __float_as_int(r.y);
    }
    __syncthreads();

    for (int i = threadIdx.x; i < n; i += 256) {
        float gi = g_s[i]; int ii = i_s[i];
        int rank = 0;
        for (int j = 0; j < n; j++) {
            float gj = g_s[j]; int ij = i_s[j];
            rank += (gj > gi || (gj == gi && ij < ii)) ? 1 : 0;
        }
        out_mask[ii] = (rank < CAPACITY) ? 1.f : 0.f;
    }
}

__global__ void aux_kernel(const int* __restrict__ cnt,
                           const float* __restrict__ imp,
                           float* __restrict__ out_aux)
{
    int lane = threadIdx.x;  // 64 threads = 1 wave
    float load = (float)min(cnt[lane], CAPACITY);
    float v = (float)N_EXPERTS * (imp[lane] / (float)N_TOKENS) * (load / (float)N_TOKENS);
    #pragma unroll
    for (int s = 32; s > 0; s >>= 1) v += __shfl_xor(v, s);
    if (lane == 0) out_aux[0] = v;
}

extern "C" void kernel_launch(void* const* d_in, const int* in_sizes, int n_in,
                              void* d_out, int out_size, void* d_ws, size_t ws_size,
                              hipStream_t stream) {
    const float* x = (const float*)d_in[0];
    const float* W = (const float*)d_in[1];
    const float* b = (const float*)d_in[2];

    float* out       = (float*)d_out;
    float* out_ids   = out;
    float* out_gates = out + 32768;
    float* out_aux   = out + 65536;
    float* out_mask  = out + 65537;

    // ws layout: [0,256) cnt | [256,512) imp | [512, 512+NK*4MB) partials | buckets
    const size_t partN = (size_t)N_TOKENS * N_EXPERTS * sizeof(float);  // 4 MB
    int NK = 1;
    if (ws_size >= 512 + 4 * partN + (size_t)N_EXPERTS * 700 * sizeof(float2)) NK = 4;
    else if (ws_size >= 512 + 2 * partN + (size_t)N_EXPERTS * 700 * sizeof(float2)) NK = 2;

    int*    cnt    = (int*)d_ws;
    float*  imp    = (float*)((char*)d_ws + 256);
    float*  part   = (float*)((char*)d_ws + 512);
    float2* bucket = (float2*)((char*)d_ws + 512 + (size_t)NK * partN);

    size_t bucket_bytes = ws_size - (512 + (size_t)NK * partN);
    int bucket_cap = (int)(bucket_bytes / (N_EXPERTS * sizeof(float2)));
    if (bucket_cap > BUCKET_CAP) bucket_cap = BUCKET_CAP;

    hipMemsetAsync(d_ws, 0, 512, stream);  // zero cnt + imp

    gemm_kernel<<<256 * NK, 256, 0, stream>>>(x, W, part, D_MODEL / NK);
    topk_kernel<<<512, 256, 0, stream>>>(part, b, NK, out_ids, out_gates,
                                         cnt, imp, bucket, bucket_cap);
    capacity_kernel<<<N_EXPERTS, 256, 0, stream>>>(cnt, bucket, out_mask, bucket_cap);
    aux_kernel<<<1, 64, 0, stream>>>(cnt, imp, out_aux);
}

// Round 3
// 793.879 us; speedup vs baseline: 1.2349x; 1.2349x over previous
//
#include <hip/hip_runtime.h>
#include <math.h>

// Problem constants
#define N_TOKENS  16384
#define D_MODEL   4096
#define N_EXPERTS 64
#define CAPACITY  308          // ceil(1.2 * 16384 / 64)
#define BUCKET_CAP 1024

// GEMM: block = 128 tokens x 64 experts; 4 waves, wave = 16 experts;
// lane = 2 tokens (lane, lane+64). K split NK ways -> partials in ws.
#define KTILE 32
#define XROW  36               // 32 + 4 pad floats; 9 float4 (odd) -> conflict-free b128

__global__ __launch_bounds__(256) void gemm_kernel(
    const float* __restrict__ x, const float* __restrict__ W,
    float* __restrict__ part,   // [NK][N_TOKENS][N_EXPERTS]
    int ksplit)
{
    __shared__ float xs[128 * XROW];   // 18432 B

    const int tid   = threadIdx.x;
    const int tg    = blockIdx.x & 127;     // token group
    const int nk    = blockIdx.x >> 7;      // k-split index
    const int tbase = tg * 128;
    const int kbase = nk * ksplit;
    const int lane  = tid & 63;
    const int wv    = __builtin_amdgcn_readfirstlane(tid >> 6);  // uniform -> scalar W path
    const int e0    = wv * 16;

    float acc0[16], acc1[16];
    #pragma unroll
    for (int i = 0; i < 16; i++) { acc0[i] = 0.f; acc1[i] = 0.f; }

    for (int kc = 0; kc < ksplit; kc += KTILE) {
        // ---- stage x tile: 128 tokens x 32 k (8 lanes span one token's 32 k: 128B lines) ----
        #pragma unroll
        for (int r = 0; r < 4; r++) {
            int idx = tid + r * 256;        // [0,1024)
            int t   = idx >> 3;             // 0..127
            int k4  = (idx & 7) << 2;       // 0..28
            float4 v = *(const float4*)&x[(size_t)(tbase + t) * D_MODEL + kbase + kc + k4];
            *(float4*)&xs[t * XROW + k4] = v;
        }
        __syncthreads();

        // ---- compute: 2 sub-chunks of 16 k ----
        #pragma unroll
        for (int kk = 0; kk < KTILE; kk += 16) {
            const float* xp0 = &xs[lane * XROW + kk];
            const float* xp1 = &xs[(lane + 64) * XROW + kk];
            float4 xa0 = *(const float4*)(xp0);
            float4 xa1 = *(const float4*)(xp0 + 4);
            float4 xa2 = *(const float4*)(xp0 + 8);
            float4 xa3 = *(const float4*)(xp0 + 12);
            float4 xb0 = *(const float4*)(xp1);
            float4 xb1 = *(const float4*)(xp1 + 4);
            float4 xb2 = *(const float4*)(xp1 + 8);
            float4 xb3 = *(const float4*)(xp1 + 12);
            const float* Wk = W + kbase + kc + kk;
            #pragma unroll
            for (int e = 0; e < 16; e++) {
                const float* wp = Wk + (size_t)(e0 + e) * D_MODEL;  // wave-uniform
                float4 w0 = *(const float4*)(wp);
                float4 w1 = *(const float4*)(wp + 4);
                float4 w2 = *(const float4*)(wp + 8);
                float4 w3 = *(const float4*)(wp + 12);
                float s0 = acc0[e], s1 = acc1[e];
                s0 = fmaf(xa0.x, w0.x, s0); s1 = fmaf(xb0.x, w0.x, s1);
                s0 = fmaf(xa0.y, w0.y, s0); s1 = fmaf(xb0.y, w0.y, s1);
                s0 = fmaf(xa0.z, w0.z, s0); s1 = fmaf(xb0.z, w0.z, s1);
                s0 = fmaf(xa0.w, w0.w, s0); s1 = fmaf(xb0.w, w0.w, s1);
                s0 = fmaf(xa1.x, w1.x, s0); s1 = fmaf(xb1.x, w1.x, s1);
                s0 = fmaf(xa1.y, w1.y, s0); s1 = fmaf(xb1.y, w1.y, s1);
                s0 = fmaf(xa1.z, w1.z, s0); s1 = fmaf(xb1.z, w1.z, s1);
                s0 = fmaf(xa1.w, w1.w, s0); s1 = fmaf(xb1.w, w1.w, s1);
                s0 = fmaf(xa2.x, w2.x, s0); s1 = fmaf(xb2.x, w2.x, s1);
                s0 = fmaf(xa2.y, w2.y, s0); s1 = fmaf(xb2.y, w2.y, s1);
                s0 = fmaf(xa2.z, w2.z, s0); s1 = fmaf(xb2.z, w2.z, s1);
                s0 = fmaf(xa2.w, w2.w, s0); s1 = fmaf(xb2.w, w2.w, s1);
                s0 = fmaf(xa3.x, w3.x, s0); s1 = fmaf(xb3.x, w3.x, s1);
                s0 = fmaf(xa3.y, w3.y, s0); s1 = fmaf(xb3.y, w3.y, s1);
                s0 = fmaf(xa3.z, w3.z, s0); s1 = fmaf(xb3.z, w3.z, s1);
                s0 = fmaf(xa3.w, w3.w, s0); s1 = fmaf(xb3.w, w3.w, s1);
                acc0[e] = s0; acc1[e] = s1;
            }
        }
        __syncthreads();
    }

    // ---- write partials ----
    {
        float4* d0 = (float4*)&part[((size_t)nk * N_TOKENS + tbase + lane) * N_EXPERTS + e0];
        d0[0] = make_float4(acc0[0],  acc0[1],  acc0[2],  acc0[3]);
        d0[1] = make_float4(acc0[4],  acc0[5],  acc0[6],  acc0[7]);
        d0[2] = make_float4(acc0[8],  acc0[9],  acc0[10], acc0[11]);
        d0[3] = make_float4(acc0[12], acc0[13], acc0[14], acc0[15]);
        float4* d1 = (float4*)&part[((size_t)nk * N_TOKENS + tbase + 64 + lane) * N_EXPERTS + e0];
        d1[0] = make_float4(acc1[0],  acc1[1],  acc1[2],  acc1[3]);
        d1[1] = make_float4(acc1[4],  acc1[5],  acc1[6],  acc1[7]);
        d1[2] = make_float4(acc1[8],  acc1[9],  acc1[10], acc1[11]);
        d1[3] = make_float4(acc1[12], acc1[13], acc1[14], acc1[15]);
    }
}

// Combine partials + bias, softmax, top-2, bucket scatter, importance.
// 512 blocks x 256; wave = 8 tokens, lane = expert. NK compile-time for unroll.
template <int NK>
__global__ __launch_bounds__(256) void topk_kernel(
    const float* __restrict__ part, const float* __restrict__ b,
    float* __restrict__ out_ids, float* __restrict__ out_gates,
    int* __restrict__ cnt, float* __restrict__ imp,
    float2* __restrict__ bucket, int bucket_cap,
    float* __restrict__ out_mask)
{
    __shared__ float imp_s[4][N_EXPERTS];
    __shared__ float res_g[4][16];     // [wave][slot]  slot = tokenj*2 + which
    __shared__ int   res_i[4][16];
    const int tid  = threadIdx.x;
    const int wave = tid >> 6;
    const int lane = tid & 63;
    const int tok0 = blockIdx.x * 32 + wave * 8;
    float impacc = 0.f;

    for (int j = 0; j < 8; j++) {
        int tok = tok0 + j;

        float v = b[lane];
        #pragma unroll
        for (int k = 0; k < NK; k++)   // independent loads, fixed order
            v += part[((size_t)k * N_TOKENS + tok) * N_EXPERTS + lane];

        float m = v;
        #pragma unroll
        for (int s = 32; s > 0; s >>= 1) m = fmaxf(m, __shfl_xor(m, s));
        float p = expf(v - m);
        float sum = p;
        #pragma unroll
        for (int s = 32; s > 0; s >>= 1) sum += __shfl_xor(sum, s);
        float prob = p / sum;
        impacc += prob;

        // argmax #1 (lowest index wins ties -> matches jax.lax.top_k)
        float bp = prob; int bi = lane;
        #pragma unroll
        for (int s = 32; s > 0; s >>= 1) {
            float op = __shfl_xor(bp, s); int oi = __shfl_xor(bi, s);
            if (op > bp || (op == bp && oi < bi)) { bp = op; bi = oi; }
        }
        // argmax #2 (exclude winner; probs >= 0 so -1 is -inf)
        float p2 = (lane == bi) ? -1.f : prob;
        float bp2 = p2; int bi2 = lane;
        #pragma unroll
        for (int s = 32; s > 0; s >>= 1) {
            float op = __shfl_xor(bp2, s); int oi = __shfl_xor(bi2, s);
            if (op > bp2 || (op == bp2 && oi < bi2)) { bp2 = op; bi2 = oi; }
        }

        if (lane == 0) {
            res_g[wave][j * 2]     = bp;  res_i[wave][j * 2]     = bi;
            res_g[wave][j * 2 + 1] = bp2; res_i[wave][j * 2 + 1] = bi2;
        }
    }

    // 16 lanes issue outputs + atomics in parallel (wave-coherent LDS, no barrier)
    __builtin_amdgcn_wave_barrier();
    if (lane < 16) {
        int slot_local = lane;
        int tok  = tok0 + (slot_local >> 1);
        int slot = tok * 2 + (slot_local & 1);
        float g  = res_g[wave][slot_local];
        int   id = res_i[wave][slot_local];
        out_ids[slot]   = (float)id;
        out_gates[slot] = g;
        int pos = atomicAdd(&cnt[id], 1);
        if (pos < bucket_cap)
            bucket[id * bucket_cap + pos] = make_float2(g, __int_as_float(slot));
        else
            out_mask[slot] = 0.f;  // overflow slot: rank >= bucket_cap > CAPACITY
    }

    imp_s[wave][lane] = impacc;
    __syncthreads();
    if (wave == 0) {
        float s = imp_s[0][lane] + imp_s[1][lane] + imp_s[2][lane] + imp_s[3][lane];
        atomicAdd(&imp[lane], s);
    }
}

// One block per expert: exact lexsort rank via O(n^2) comparison in LDS.
__global__ __launch_bounds__(256) void capacity_kernel(
    const int* __restrict__ cnt, const float2* __restrict__ bucket,
    float* __restrict__ out_mask, int bucket_cap)
{
    __shared__ float g_s[BUCKET_CAP];
    __shared__ int   i_s[BUCKET_CAP];
    const int e = blockIdx.x;
    int n = cnt[e];
    if (n > bucket_cap) n = bucket_cap;

    for (int i = threadIdx.x; i < n; i += 256) {
        float2 r = bucket[e * bucket_cap + i];
        g_s[i] = r.x;
        i_s[i] = __float_as_int(r.y);
    }
    __syncthreads();

    for (int i = threadIdx.x; i < n; i += 256) {
        float gi = g_s[i]; int ii = i_s[i];
        int rank = 0;
        for (int j = 0; j < n; j++) {
            float gj = g_s[j]; int ij = i_s[j];
            rank += (gj > gi || (gj == gi && ij < ii)) ? 1 : 0;
        }
        out_mask[ii] = (rank < CAPACITY) ? 1.f : 0.f;
    }
}

__global__ void aux_kernel(const int* __restrict__ cnt,
                           const float* __restrict__ imp,
                           float* __restrict__ out_aux)
{
    int lane = threadIdx.x;  // 64 threads = 1 wave
    float load = (float)min(cnt[lane], CAPACITY);
    float v = (float)N_EXPERTS * (imp[lane] / (float)N_TOKENS) * (load / (float)N_TOKENS);
    #pragma unroll
    for (int s = 32; s > 0; s >>= 1) v += __shfl_xor(v, s);
    if (lane == 0) out_aux[0] = v;
}

extern "C" void kernel_launch(void* const* d_in, const int* in_sizes, int n_in,
                              void* d_out, int out_size, void* d_ws, size_t ws_size,
                              hipStream_t stream) {
    const float* x = (const float*)d_in[0];
    const float* W = (const float*)d_in[1];
    const float* b = (const float*)d_in[2];

    float* out       = (float*)d_out;
    float* out_ids   = out;
    float* out_gates = out + 32768;
    float* out_aux   = out + 65536;
    float* out_mask  = out + 65537;

    // ws: [0,256) cnt | [256,512) imp | [512, 512+NK*4MB) partials | buckets
    const size_t partN  = (size_t)N_TOKENS * N_EXPERTS * sizeof(float);  // 4 MB
    const size_t bktMin = (size_t)N_EXPERTS * 700 * sizeof(float2);
    int NK = 1;
    if      (ws_size >= 512 + 8 * partN + bktMin) NK = 8;
    else if (ws_size >= 512 + 4 * partN + bktMin) NK = 4;
    else if (ws_size >= 512 + 2 * partN + bktMin) NK = 2;

    int*    cnt    = (int*)d_ws;
    float*  imp    = (float*)((char*)d_ws + 256);
    float*  part   = (float*)((char*)d_ws + 512);
    float2* bucket = (float2*)((char*)d_ws + 512 + (size_t)NK * partN);

    size_t bucket_bytes = ws_size - (512 + (size_t)NK * partN);
    int bucket_cap = (int)(bucket_bytes / (N_EXPERTS * sizeof(float2)));
    if (bucket_cap > BUCKET_CAP) bucket_cap = BUCKET_CAP;

    hipMemsetAsync(d_ws, 0, 512, stream);  // zero cnt + imp

    gemm_kernel<<<128 * NK, 256, 0, stream>>>(x, W, part, D_MODEL / NK);
    switch (NK) {
      case 8: topk_kernel<8><<<512, 256, 0, stream>>>(part, b, out_ids, out_gates, cnt, imp, bucket, bucket_cap, out_mask); break;
      case 4: topk_kernel<4><<<512, 256, 0, stream>>>(part, b, out_ids, out_gates, cnt, imp, bucket, bucket_cap, out_mask); break;
      case 2: topk_kernel<2><<<512, 256, 0, stream>>>(part, b, out_ids, out_gates, cnt, imp, bucket, bucket_cap, out_mask); break;
      default: topk_kernel<1><<<512, 256, 0, stream>>>(part, b, out_ids, out_gates, cnt, imp, bucket, bucket_cap, out_mask); break;
    }
    capacity_kernel<<<N_EXPERTS, 256, 0, stream>>>(cnt, bucket, out_mask, bucket_cap);
    aux_kernel<<<1, 64, 0, stream>>>(cnt, imp, out_aux);
}

// Round 5
// 722.211 us; speedup vs baseline: 1.3575x; 1.0992x over previous
//
#include <hip/hip_runtime.h>
#include <math.h>

// Problem constants
#define N_TOKENS  16384
#define D_MODEL   4096
#define N_EXPERTS 64
#define CAPACITY  308          // ceil(1.2 * 16384 / 64)
#define BUCKET_CAP 1024

// GEMM config: MFMA 16x16x32 bf16, exact 3-way split / 6-product fp32 emulation.
// Block = 64 tokens x 64 experts, 4 waves (wave = 16 tokens), split-K NK=4.
#define NK     4
#define KSPLIT (D_MODEL / NK)   // 1024
#define KTILE  64
#define MTILE  64

typedef __attribute__((ext_vector_type(8))) short bf16x8;
typedef __attribute__((ext_vector_type(4))) float f32x4;

__device__ __forceinline__ unsigned short bf16_rne(float f) {
    unsigned u = __float_as_uint(f);
    u += 0x7fffu + ((u >> 16) & 1u);
    return (unsigned short)(u >> 16);
}
__device__ __forceinline__ float bf16_to_f32(unsigned short h) {
    return __uint_as_float(((unsigned)h) << 16);
}
// Exact 3-way RNE split: f == hi + mid + lo (fp32 24-bit mantissa -> 8+8+8).
__device__ __forceinline__ void split3(float f, unsigned short& h,
                                       unsigned short& m, unsigned short& l) {
    h = bf16_rne(f);
    float r1 = f - bf16_to_f32(h);   // exact, <= 16 significant bits
    m = bf16_rne(r1);
    float r2 = r1 - bf16_to_f32(m);  // exact, <= 8 significant bits
    l = bf16_rne(r2);                // exact
}

// ---- split W once: W[64][4096] fp32 -> whi/wmid/wlo bf16 ----
__global__ __launch_bounds__(256) void wsplit_kernel(
    const float* __restrict__ W,
    unsigned short* __restrict__ whi, unsigned short* __restrict__ wmid,
    unsigned short* __restrict__ wlo)
{
    int i = (blockIdx.x * 256 + threadIdx.x) * 4;
    float4 w = *(const float4*)&W[i];
    float e[4] = {w.x, w.y, w.z, w.w};
    ushort4 h, m, l;
    unsigned short* hp = &h.x; unsigned short* mp = &m.x; unsigned short* lp = &l.x;
    #pragma unroll
    for (int j = 0; j < 4; j++) split3(e[j], hp[j], mp[j], lp[j]);
    *(ushort4*)&whi[i]  = h;
    *(ushort4*)&wmid[i] = m;
    *(ushort4*)&wlo[i]  = l;
}

// ---- main GEMM: x[16384][4096] @ W^T -> part[NK][16384][64] ----
__global__ __launch_bounds__(256) void gemm_kernel(
    const float* __restrict__ x,
    const unsigned short* __restrict__ whi,
    const unsigned short* __restrict__ wmid,
    const unsigned short* __restrict__ wlo,
    float* __restrict__ part)
{
    // XOR-swizzled bf16 tiles: row = token (64), 8 chunks of 8 bf16 per row.
    // chunk (r,q) lives at ushort index r*64 + ((q ^ (r&7))*8) -> conflict-free b128.
    __shared__ unsigned short xhi[MTILE * KTILE];    // 8 KB
    __shared__ unsigned short xmid[MTILE * KTILE];   // 8 KB
    __shared__ unsigned short xlo[MTILE * KTILE];    // 8 KB

    const int tid   = threadIdx.x;
    const int tg    = blockIdx.x & 255;
    const int nk    = blockIdx.x >> 8;
    const int tbase = tg * MTILE;
    const int kbase = nk * KSPLIT;
    const int lane  = tid & 63;
    const int wv    = tid >> 6;

    // staging: thread covers row sr, k = sk0..sk0+16 (16 fp32 -> 2 chunks/split)
    const int sr  = tid >> 2;
    const int sk0 = (tid & 3) * 16;
    const int sq  = (tid & 3) * 2;
    const float* xsrc = &x[(size_t)(tbase + sr) * D_MODEL + kbase + sk0];

    // MFMA fragment indices (verified mappings: A[m=lane&15][k=quad*8+j],
    // C/D row=quad*4+reg, col=lane&15)
    const int arow = wv * 16 + (lane & 15);   // token row within tile
    const int akq  = lane >> 4;               // k-quad 0..3
    const int nrow = lane & 15;               // expert row within n-tile

    f32x4 acc[4];
    #pragma unroll
    for (int nt = 0; nt < 4; nt++)
        #pragma unroll
        for (int r = 0; r < 4; r++) acc[nt][r] = 0.f;

    float pf[16];
    {   // prefetch tile 0
        float4 a0 = *(const float4*)(xsrc);
        float4 a1 = *(const float4*)(xsrc + 4);
        float4 a2 = *(const float4*)(xsrc + 8);
        float4 a3 = *(const float4*)(xsrc + 12);
        pf[0]=a0.x; pf[1]=a0.y; pf[2]=a0.z; pf[3]=a0.w;
        pf[4]=a1.x; pf[5]=a1.y; pf[6]=a1.z; pf[7]=a1.w;
        pf[8]=a2.x; pf[9]=a2.y; pf[10]=a2.z; pf[11]=a2.w;
        pf[12]=a3.x; pf[13]=a3.y; pf[14]=a3.z; pf[15]=a3.w;
    }

    for (int kc = 0; kc < KSPLIT; kc += KTILE) {
        // ---- convert prefetched fp32 -> hi/mid/lo bf16, write swizzled LDS ----
        #pragma unroll
        for (int c = 0; c < 2; c++) {
            bf16x8 vh, vm, vl;
            #pragma unroll
            for (int j = 0; j < 8; j++) {
                unsigned short h, m, l;
                split3(pf[c * 8 + j], h, m, l);
                vh[j] = (short)h; vm[j] = (short)m; vl[j] = (short)l;
            }
            int p = (sq + c) ^ (sr & 7);
            *(bf16x8*)&xhi[sr * 64 + p * 8]  = vh;
            *(bf16x8*)&xmid[sr * 64 + p * 8] = vm;
            *(bf16x8*)&xlo[sr * 64 + p * 8]  = vl;
        }
        __syncthreads();

        // ---- issue prefetch of next tile (overlaps MFMA below) ----
        if (kc + KTILE < KSPLIT) {
            const float* nsrc = xsrc + kc + KTILE;
            float4 a0 = *(const float4*)(nsrc);
            float4 a1 = *(const float4*)(nsrc + 4);
            float4 a2 = *(const float4*)(nsrc + 8);
            float4 a3 = *(const float4*)(nsrc + 12);
            pf[0]=a0.x; pf[1]=a0.y; pf[2]=a0.z; pf[3]=a0.w;
            pf[4]=a1.x; pf[5]=a1.y; pf[6]=a1.z; pf[7]=a1.w;
            pf[8]=a2.x; pf[9]=a2.y; pf[10]=a2.z; pf[11]=a2.w;
            pf[12]=a3.x; pf[13]=a3.y; pf[14]=a3.z; pf[15]=a3.w;
        }

        // ---- MFMA: 2 k-steps of 32, 4 n-tiles, 6 products each ----
        #pragma unroll
        for (int s = 0; s < 2; s++) {
            int chA = (s * 4 + akq) ^ (arow & 7);
            bf16x8 ahi = *(bf16x8*)&xhi[arow * 64 + chA * 8];
            bf16x8 ami = *(bf16x8*)&xmid[arow * 64 + chA * 8];
            bf16x8 alo = *(bf16x8*)&xlo[arow * 64 + chA * 8];
            size_t koff = (size_t)(kbase + kc + s * 32 + akq * 8);
            #pragma unroll
            for (int nt = 0; nt < 4; nt++) {
                size_t boff = (size_t)(nt * 16 + nrow) * D_MODEL + koff;
                bf16x8 bhi = *(const bf16x8*)&whi[boff];
                bf16x8 bmi = *(const bf16x8*)&wmid[boff];
                bf16x8 blo = *(const bf16x8*)&wlo[boff];
                // magnitude-ordered: 1, 2^-8, 2^-8, 2^-16, 2^-16, 2^-16
                acc[nt] = __builtin_amdgcn_mfma_f32_16x16x32_bf16(ahi, bhi, acc[nt], 0, 0, 0);
                acc[nt] = __builtin_amdgcn_mfma_f32_16x16x32_bf16(ahi, bmi, acc[nt], 0, 0, 0);
                acc[nt] = __builtin_amdgcn_mfma_f32_16x16x32_bf16(ami, bhi, acc[nt], 0, 0, 0);
                acc[nt] = __builtin_amdgcn_mfma_f32_16x16x32_bf16(ahi, blo, acc[nt], 0, 0, 0);
                acc[nt] = __builtin_amdgcn_mfma_f32_16x16x32_bf16(ami, bmi, acc[nt], 0, 0, 0);
                acc[nt] = __builtin_amdgcn_mfma_f32_16x16x32_bf16(alo, bhi, acc[nt], 0, 0, 0);
            }
        }
        __syncthreads();
    }

    // ---- write partials: token = tbase + wv*16 + akq*4 + r, expert = nt*16 + nrow
    #pragma unroll
    for (int nt = 0; nt < 4; nt++) {
        #pragma unroll
        for (int r = 0; r < 4; r++) {
            int tok = tbase + wv * 16 + akq * 4 + r;
            part[((size_t)nk * N_TOKENS + tok) * N_EXPERTS + nt * 16 + nrow] = acc[nt][r];
        }
    }
}

// Combine partials + bias, softmax, top-2, bucket scatter, importance.
__global__ __launch_bounds__(256) void topk_kernel(
    const float* __restrict__ part, const float* __restrict__ b,
    float* __restrict__ out_ids, float* __restrict__ out_gates,
    int* __restrict__ cnt, float* __restrict__ imp,
    float2* __restrict__ bucket, int bucket_cap,
    float* __restrict__ out_mask)
{
    __shared__ float imp_s[4][N_EXPERTS];
    __shared__ float res_g[4][16];
    __shared__ int   res_i[4][16];
    const int tid  = threadIdx.x;
    const int wave = tid >> 6;
    const int lane = tid & 63;
    const int tok0 = blockIdx.x * 32 + wave * 8;
    float impacc = 0.f;

    for (int j = 0; j < 8; j++) {
        int tok = tok0 + j;
        float v = b[lane];
        #pragma unroll
        for (int k = 0; k < NK; k++)
            v += part[((size_t)k * N_TOKENS + tok) * N_EXPERTS + lane];

        float m = v;
        #pragma unroll
        for (int s = 32; s > 0; s >>= 1) m = fmaxf(m, __shfl_xor(m, s));
        float p = expf(v - m);
        float sum = p;
        #pragma unroll
        for (int s = 32; s > 0; s >>= 1) sum += __shfl_xor(sum, s);
        float prob = p / sum;
        impacc += prob;

        float bp = prob; int bi = lane;
        #pragma unroll
        for (int s = 32; s > 0; s >>= 1) {
            float op = __shfl_xor(bp, s); int oi = __shfl_xor(bi, s);
            if (op > bp || (op == bp && oi < bi)) { bp = op; bi = oi; }
        }
        float p2 = (lane == bi) ? -1.f : prob;
        float bp2 = p2; int bi2 = lane;
        #pragma unroll
        for (int s = 32; s > 0; s >>= 1) {
            float op = __shfl_xor(bp2, s); int oi = __shfl_xor(bi2, s);
            if (op > bp2 || (op == bp2 && oi < bi2)) { bp2 = op; bi2 = oi; }
        }

        if (lane == 0) {
            res_g[wave][j * 2]     = bp;  res_i[wave][j * 2]     = bi;
            res_g[wave][j * 2 + 1] = bp2; res_i[wave][j * 2 + 1] = bi2;
        }
    }

    __builtin_amdgcn_wave_barrier();
    if (lane < 16) {
        int tok  = tok0 + (lane >> 1);
        int slot = tok * 2 + (lane & 1);
        float g  = res_g[wave][lane];
        int   id = res_i[wave][lane];
        out_ids[slot]   = (float)id;
        out_gates[slot] = g;
        int pos = atomicAdd(&cnt[id], 1);
        if (pos < bucket_cap)
            bucket[id * bucket_cap + pos] = make_float2(g, __int_as_float(slot));
        else
            out_mask[slot] = 0.f;
    }

    imp_s[wave][lane] = impacc;
    __syncthreads();
    if (wave == 0) {
        float s = imp_s[0][lane] + imp_s[1][lane] + imp_s[2][lane] + imp_s[3][lane];
        atomicAdd(&imp[lane], s);
    }
}

// One block per expert: exact lexsort rank via O(n^2) comparison in LDS.
__global__ __launch_bounds__(256) void capacity_kernel(
    const int* __restrict__ cnt, const float2* __restrict__ bucket,
    float* __restrict__ out_mask, int bucket_cap)
{
    __shared__ float g_s[BUCKET_CAP];
    __shared__ int   i_s[BUCKET_CAP];
    const int e = blockIdx.x;
    int n = cnt[e];
    if (n > bucket_cap) n = bucket_cap;

    for (int i = threadIdx.x; i < n; i += 256) {
        float2 r = bucket[e * bucket_cap + i];
        g_s[i] = r.x;
        i_s[i] = __float_as_int(r.y);
    }
    __syncthreads();

    for (int i = threadIdx.x; i < n; i += 256) {
        float gi = g_s[i]; int ii = i_s[i];
        int rank = 0;
        for (int j = 0; j < n; j++) {
            float gj = g_s[j]; int ij = i_s[j];
            rank += (gj > gi || (gj == gi && ij < ii)) ? 1 : 0;
        }
        out_mask[ii] = (rank < CAPACITY) ? 1.f : 0.f;
    }
}

__global__ void aux_kernel(const int* __restrict__ cnt,
                           const float* __restrict__ imp,
                           float* __restrict__ out_aux)
{
    int lane = threadIdx.x;
    float load = (float)min(cnt[lane], CAPACITY);
    float v = (float)N_EXPERTS * (imp[lane] / (float)N_TOKENS) * (load / (float)N_TOKENS);
    #pragma unroll
    for (int s = 32; s > 0; s >>= 1) v += __shfl_xor(v, s);
    if (lane == 0) out_aux[0] = v;
}

extern "C" void kernel_launch(void* const* d_in, const int* in_sizes, int n_in,
                              void* d_out, int out_size, void* d_ws, size_t ws_size,
                              hipStream_t stream) {
    const float* x = (const float*)d_in[0];
    const float* W = (const float*)d_in[1];
    const float* b = (const float*)d_in[2];

    float* out       = (float*)d_out;
    float* out_ids   = out;
    float* out_gates = out + 32768;
    float* out_aux   = out + 65536;
    float* out_mask  = out + 65537;

    // ws: [0,256) cnt | [256,512) imp | part NK*4MB | whi/wmid/wlo 3*512KB | buckets
    const size_t partN = (size_t)N_TOKENS * N_EXPERTS * sizeof(float);          // 4 MB
    const size_t wN    = (size_t)N_EXPERTS * D_MODEL * sizeof(unsigned short);  // 512 KB

    int*            cnt    = (int*)d_ws;
    float*          imp    = (float*)((char*)d_ws + 256);
    float*          part   = (float*)((char*)d_ws + 512);
    unsigned short* whi    = (unsigned short*)((char*)d_ws + 512 + NK * partN);
    unsigned short* wmid   = (unsigned short*)((char*)d_ws + 512 + NK * partN + wN);
    unsigned short* wlo    = (unsigned short*)((char*)d_ws + 512 + NK * partN + 2 * wN);
    float2*         bucket = (float2*)((char*)d_ws + 512 + NK * partN + 3 * wN);

    size_t used = 512 + NK * partN + 3 * wN;
    int bucket_cap = (ws_size > used) ? (int)((ws_size - used) / (N_EXPERTS * sizeof(float2))) : 0;
    if (bucket_cap > BUCKET_CAP) bucket_cap = BUCKET_CAP;

    hipMemsetAsync(d_ws, 0, 512, stream);

    wsplit_kernel<<<(N_EXPERTS * D_MODEL) / (256 * 4), 256, 0, stream>>>(W, whi, wmid, wlo);
    gemm_kernel<<<256 * NK, 256, 0, stream>>>(x, whi, wmid, wlo, part);
    topk_kernel<<<512, 256, 0, stream>>>(part, b, out_ids, out_gates,
                                         cnt, imp, bucket, bucket_cap, out_mask);
    capacity_kernel<<<N_EXPERTS, 256, 0, stream>>>(cnt, bucket, out_mask, bucket_cap);
    aux_kernel<<<1, 64, 0, stream>>>(cnt, imp, out_aux);
}